// Round 9
// baseline (406.660 us; speedup 1.0000x reference)
//
#include <hip/hip_runtime.h>
#include <hip/hip_bf16.h>

typedef __hip_bfloat16 bf16;
using short8  = __attribute__((ext_vector_type(8))) short;
using float4_ = __attribute__((ext_vector_type(4))) float;

#define B_    4
#define C_    192
#define NN    16384   // 128*128
#define HEADS 4
#define CHD   48
#define TOT   1152    // 576 qkv + 192 q_mut + 384 kv_mut

__device__ __forceinline__ float b2f(bf16 v) { return __bfloat162float(v); }
__device__ __forceinline__ float s2f(short s) {
    return __uint_as_float(((unsigned)(unsigned short)s) << 16);
}

// ---------------------------------------------------------------------------
// kprep_w: concat+cast 1x1 weights -> Wb[1152][192] bf16.
// ---------------------------------------------------------------------------
__global__ __launch_bounds__(256) void kprep_w(
    const float* __restrict__ qkv_w, const float* __restrict__ qm_w,
    const float* __restrict__ kvm_w, bf16* __restrict__ Wb)
{
    int i = blockIdx.x * 256 + threadIdx.x;
    if (i >= TOT * C_) return;
    int r = i / C_, c = i % C_;
    float v = (r < 576) ? qkv_w[r * C_ + c]
            : (r < 768) ? qm_w[(r - 576) * C_ + c]
                        : kvm_w[(r - 768) * C_ + c];
    Wb[i] = __float2bfloat16(v);
}

// ---------------------------------------------------------------------------
// kgemm: per-batch Y[1152][16384] = Wb[1152][192] x X[192][16384], bf16 MFMA.
// v4: B-operand staged DIRECTLY from raw f32 x/x_hidden with in-LDS
// transpose+cast (k5-v5 pattern: c = lane, conflict-free column writes)
// -> kprep_x kernel and Xt buffer eliminated (-100 MB HBM, -4 launches).
// Tile/MFMA structure = proven round-1 64x128 (27.6 KB LDS, high occupancy).
// Same __float2bfloat16 per element, same sB layout -> Y bit-exact.
// ---------------------------------------------------------------------------
__global__ __launch_bounds__(256) void kgemm(
    const bf16* __restrict__ Wb, const float* __restrict__ x,
    const float* __restrict__ xh, int b, bf16* __restrict__ Y)
{
    const int nt0 = blockIdx.x * 128;
    const int mt0 = blockIdx.y * 64;
    const int tid = threadIdx.x;
    const float* xsrc = (mt0 >= 768 ? xh : x) + (size_t)b * C_ * NN;

    __shared__ short sA[64][72];
    __shared__ short sB[128][72];   // [n][k_local]

    const int wave = tid >> 6, lane = tid & 63;
    const int mw = (wave & 1) * 32, nw = (wave >> 1) * 64;
    const int lm = lane & 15, lq = lane >> 4;

    float4_ acc[2][4];
    #pragma unroll
    for (int i = 0; i < 2; ++i)
        #pragma unroll
        for (int j = 0; j < 4; ++j)
            acc[i][j] = (float4_){0.f, 0.f, 0.f, 0.f};

    for (int kc = 0; kc < 192; kc += 64) {
        __syncthreads();
        // A stage: 64 rows x 64 k bf16 from Wb (unchanged)
        {
            int r = tid >> 3, c8 = (tid & 7) * 8;
            #pragma unroll
            for (int it = 0; it < 2; ++it, r += 32)
                *(short8*)&sA[r][c8] =
                    *(const short8*)&Wb[(size_t)(mt0 + r) * C_ + kc + c8];
        }
        // B stage: transpose+cast from f32 x. c = tid&63 (lane-owned row),
        // ng = (tid>>6)+4*it covers 32 float4-granules of 128 n.
        // Writes: 64 consecutive shorts per (ng,j) -> 2 lanes/bank (free).
        {
            const int c = tid & 63;
            const int ngb = tid >> 6;
            const float* xr = &xsrc[(size_t)(kc + c) * NN + nt0];
            #pragma unroll
            for (int it = 0; it < 8; ++it) {
                const int ng = ngb + it * 4;          // 0..31
                const float4_ v = *(const float4_*)&xr[ng * 4];
                #pragma unroll
                for (int j = 0; j < 4; ++j) {
                    bf16 h = __float2bfloat16(v[j]);
                    sB[ng * 4 + j][c] = *reinterpret_cast<short*>(&h);
                }
            }
        }
        __syncthreads();
        #pragma unroll
        for (int kk = 0; kk < 64; kk += 32) {
            short8 af[2], bfr[4];
            const int ko = kk + lq * 8;
            #pragma unroll
            for (int i = 0; i < 2; ++i)
                af[i] = *(const short8*)&sA[mw + i * 16 + lm][ko];
            #pragma unroll
            for (int j = 0; j < 4; ++j)
                bfr[j] = *(const short8*)&sB[nw + j * 16 + lm][ko];
            #pragma unroll
            for (int i = 0; i < 2; ++i)
                #pragma unroll
                for (int j = 0; j < 4; ++j)
                    acc[i][j] = __builtin_amdgcn_mfma_f32_16x16x32_bf16(
                        af[i], bfr[j], acc[i][j], 0, 0, 0);
        }
    }
    #pragma unroll
    for (int i = 0; i < 2; ++i)
        #pragma unroll
        for (int j = 0; j < 4; ++j) {
            const int n = nt0 + nw + j * 16 + lm;
            #pragma unroll
            for (int r = 0; r < 4; ++r) {
                const int m = mt0 + mw + i * 16 + lq * 4 + r;
                Y[(size_t)m * NN + n] = __float2bfloat16(acc[i][j][r]);
            }
        }
}

// ---------------------------------------------------------------------------
// kdw: per-batch depthwise 3x3 Y -> QT[b], register-resident row-sliding.
// v2: halo via lane shuffles (bit-exact, 3x fewer VMEM ops).
// ---------------------------------------------------------------------------
__device__ __forceinline__ void kdw_load_row(
    float* r, const bf16* __restrict__ Yc, int row, int x0, int lane)
{
    float f[8];
    if (row >= 0 && row <= 127) {
        short8 v = *(const short8*)(Yc + row * 128 + x0);
        #pragma unroll
        for (int i = 0; i < 8; ++i) f[i] = s2f(v[i]);
    } else {
        #pragma unroll
        for (int i = 0; i < 8; ++i) f[i] = 0.f;
    }
    const float lf = __shfl(f[7], lane - 1);
    const float rf = __shfl(f[0], lane + 1);
    r[0] = (x0 > 0)   ? lf : 0.f;
    r[9] = (x0 < 120) ? rf : 0.f;
    #pragma unroll
    for (int i = 0; i < 8; ++i) r[i + 1] = f[i];
}

__global__ __launch_bounds__(256) void kdw(
    const bf16* __restrict__ Y,
    const float* __restrict__ qkv_dw, const float* __restrict__ qm_dw,
    const float* __restrict__ kvm_dw, int b, bf16* __restrict__ QT,
    float* __restrict__ nrmsq)
{
    const int ch  = blockIdx.x;
    const int tid = threadIdx.x;
    const int tx = tid & 15, ty = tid >> 4;
    const int lane = tid & 63;
    const int x0 = tx * 8;
    const int y0 = blockIdx.y * 64 + ty * 4;

    const float* dwp = (ch < 576) ? qkv_dw + (size_t)ch * 9
                     : (ch < 768) ? qm_dw + (size_t)(ch - 576) * 9
                                  : kvm_dw + (size_t)(ch - 768) * 9;
    float w[9];
    #pragma unroll
    for (int i = 0; i < 9; ++i) w[i] = dwp[i];

    const bf16* Yc = Y + (size_t)ch * NN;
    bf16* qout = QT + ((size_t)b * TOT + ch) * NN;

    float r0[10], r1[10], r2[10];
    kdw_load_row(r0, Yc, y0 - 1, x0, lane);
    kdw_load_row(r1, Yc, y0,     x0, lane);

    float ssq = 0.f;
    #pragma unroll
    for (int yy = 0; yy < 4; ++yy) {
        kdw_load_row(r2, Yc, y0 + yy + 1, x0, lane);
        short8 sv;
        #pragma unroll
        for (int xx = 0; xx < 8; ++xx) {
            float s = w[0] * r0[xx] + w[1] * r0[xx + 1] + w[2] * r0[xx + 2]
                    + w[3] * r1[xx] + w[4] * r1[xx + 1] + w[5] * r1[xx + 2]
                    + w[6] * r2[xx] + w[7] * r2[xx + 1] + w[8] * r2[xx + 2];
            ssq += s * s;
            bf16 h = __float2bfloat16(s);
            sv[xx] = *reinterpret_cast<short*>(&h);
        }
        *(short8*)&qout[(size_t)(y0 + yy) * 128 + x0] = sv;
        #pragma unroll
        for (int i = 0; i < 10; ++i) { r0[i] = r1[i]; r1[i] = r2[i]; }
    }

    // fused sum-of-squares for norm classes q/k/q_mut/k_mut
    int cls = -1, ci = 0;
    if (ch < 192)                    { cls = 0; ci = ch; }
    else if (ch < 384)               { cls = 1; ci = ch - 192; }
    else if (ch >= 576 && ch < 768)  { cls = 2; ci = ch - 576; }
    else if (ch >= 768 && ch < 960)  { cls = 3; ci = ch - 768; }
    if (cls >= 0) {
        #pragma unroll
        for (int off = 32; off > 0; off >>= 1) ssq += __shfl_down(ssq, off);
        __shared__ float red[4];
        if ((tid & 63) == 0) red[tid >> 6] = ssq;
        __syncthreads();
        if (tid == 0)
            atomicAdd(&nrmsq[(b * 4 + cls) * 192 + ci],
                      red[0] + red[1] + red[2] + red[3]);
    }
}

// ---------------------------------------------------------------------------
// k3_mfma: Gram partials via MFMA, operands direct from global.
// grid (32 n-chunks of 512, 8 = t*4+h, 4 b), block 256 = 4 waves.
// ---------------------------------------------------------------------------
__global__ __launch_bounds__(256) void k3_mfma(
    const bf16* __restrict__ QT, float* __restrict__ Gpart)
{
    const int chunk = blockIdx.x;
    const int t = blockIdx.y >> 2, h = blockIdx.y & 3;
    const int b = blockIdx.z;
    const int qch = (t == 0 ? 0 : 576) + h * CHD;
    const int kch = (t == 0 ? 192 : 768) + h * CHD;
    const bf16* qp = QT + ((size_t)b * TOT + qch) * NN;
    const bf16* kp = QT + ((size_t)b * TOT + kch) * NN;

    const int tid = threadIdx.x;
    const int wave = tid >> 6, lane = tid & 63;
    const int lm = lane & 15, lq = lane >> 4;
    const int n0 = chunk * 512 + wave * 128;

    float4_ acc[3][3];
    #pragma unroll
    for (int i = 0; i < 3; ++i)
        #pragma unroll
        for (int j = 0; j < 3; ++j)
            acc[i][j] = (float4_){0.f, 0.f, 0.f, 0.f};

    #pragma unroll
    for (int kk = 0; kk < 128; kk += 32) {
        short8 af[3], bfr[3];
        const int ko = n0 + kk + lq * 8;
        #pragma unroll
        for (int i = 0; i < 3; ++i)
            af[i] = *(const short8*)&qp[(size_t)(i * 16 + lm) * NN + ko];
        #pragma unroll
        for (int j = 0; j < 3; ++j)
            bfr[j] = *(const short8*)&kp[(size_t)(j * 16 + lm) * NN + ko];
        #pragma unroll
        for (int i = 0; i < 3; ++i)
            #pragma unroll
            for (int j = 0; j < 3; ++j)
                acc[i][j] = __builtin_amdgcn_mfma_f32_16x16x32_bf16(
                    af[i], bfr[j], acc[i][j], 0, 0, 0);
    }

    __shared__ float sW[4][48 * 49];
    #pragma unroll
    for (int i = 0; i < 3; ++i)
        #pragma unroll
        for (int j = 0; j < 3; ++j)
            #pragma unroll
            for (int r = 0; r < 4; ++r)
                sW[wave][(i * 16 + lq * 4 + r) * 49 + j * 16 + lm] = acc[i][j][r];
    __syncthreads();

    const int gidx = ((t * 4 + b) * 4 + h);
    float* Gp = Gpart + ((size_t)gidx * 32 + chunk) * 2304;
    for (int idx = tid; idx < 2304; idx += 256) {
        const int c = idx / 48, d = idx % 48;
        Gp[idx] = sW[0][c * 49 + d] + sW[1][c * 49 + d]
                + sW[2][c * 49 + d] + sW[3][c * 49 + d];
    }
}

// ---------------------------------------------------------------------------
// kred: G[gidx][2304] = sum over 32 chunks of Gpart[gidx][chunk][2304].
// ---------------------------------------------------------------------------
__global__ __launch_bounds__(256) void kred(
    const float* __restrict__ Gpart, float* __restrict__ G)
{
    const int idx = blockIdx.x * 256 + threadIdx.x;
    if (idx >= 32 * 2304) return;
    const int g = idx / 2304, i = idx % 2304;
    const float* p = Gpart + (size_t)g * 32 * 2304 + i;
    float s = 0.f;
    #pragma unroll
    for (int ch = 0; ch < 32; ++ch) s += p[(size_t)ch * 2304];
    G[(size_t)g * 2304 + i] = s;
}

// ---------------------------------------------------------------------------
// k4a_softmax: wave-per-row softmax of the 32 48x48 logit matrices.
// ---------------------------------------------------------------------------
__global__ __launch_bounds__(256) void k4a_softmax(
    const float* __restrict__ G, const float* __restrict__ nrmsq,
    const float* __restrict__ tq, const float* __restrict__ tm,
    float* __restrict__ P)
{
    const int gidx = blockIdx.x;            // (t*4 + b)*4 + h
    const int h = gidx & 3, tb = gidx >> 2;
    const int b = tb & 3, t = tb >> 2;
    const float* Gp = G + (size_t)gidx * 2304;
    float* Pp = P + (size_t)gidx * 2304;

    const int tid = threadIdx.x;
    const int wave = tid >> 6, lane = tid & 63;
    const int clsq = (t == 0) ? 0 : 2, clsk = (t == 0) ? 1 : 3;
    const float tmp = (t == 0 ? tq[h] : tm[h]);

    float nk = 1.f;
    if (lane < 48)
        nk = fmaxf(sqrtf(fmaxf(nrmsq[(b * 4 + clsk) * 192 + h * 48 + lane], 0.f)),
                   1e-12f);
    const float sk = tmp / nk;   // per-lane (per-d) scale

    const int c0 = blockIdx.y * 12 + wave * 3;
    #pragma unroll
    for (int cc = 0; cc < 3; ++cc) {
        const int c = c0 + cc;
        const float nq =
            fmaxf(sqrtf(fmaxf(nrmsq[(b * 4 + clsq) * 192 + h * 48 + c], 0.f)),
                  1e-12f);
        float L = -1e30f;
        if (lane < 48) L = Gp[c * 48 + lane] * sk / nq;
        float mx = L;
        #pragma unroll
        for (int off = 32; off > 0; off >>= 1)
            mx = fmaxf(mx, __shfl_xor(mx, off));
        float e = (lane < 48) ? expf(L - mx) : 0.f;
        float sum = e;
        #pragma unroll
        for (int off = 32; off > 0; off >>= 1)
            sum += __shfl_xor(sum, off);
        if (lane < 48) Pp[c * 48 + lane] = e / sum;
    }
}

// ---------------------------------------------------------------------------
// k4b_fold: Mb[b][o][t*192+h*48+d] = sum_c proj[o][t*192+h*48+c] * P[c][d].
// ---------------------------------------------------------------------------
__global__ __launch_bounds__(256) void k4b_fold(
    const float* __restrict__ P, const float* __restrict__ proj_w,
    bf16* __restrict__ Mb)
{
    const int gidx = blockIdx.x;
    const int h = gidx & 3, tb = gidx >> 2;
    const int b = tb & 3, t = tb >> 2;
    const int o0 = blockIdx.y * 48;
    const int colb = t * 192 + h * 48;

    __shared__ float sP[48][49];   // sP[c][d]
    __shared__ float sW[48][49];   // sW[o_local][c]
    const int tid = threadIdx.x;
    const float* Pp = P + (size_t)gidx * 2304;

    for (int idx = tid; idx < 2304; idx += 256) {
        const int r = idx / 48, q = idx % 48;
        sP[r][q] = Pp[idx];
        sW[r][q] = proj_w[(size_t)(o0 + r) * 384 + colb + q];
    }
    __syncthreads();

    for (int idx = tid; idx < 2304; idx += 256) {
        const int o = idx / 48, d = idx % 48;
        float s = 0.f;
        #pragma unroll
        for (int c = 0; c < 48; ++c) s += sW[o][c] * sP[c][d];
        Mb[((size_t)b * 192 + o0 + o) * 384 + colb + d] = __float2bfloat16(s);
    }
}

// ---------------------------------------------------------------------------
// k5_mfma: out[b][192][16384] = Mb[b][192][384] x V, V taken DIRECTLY from
// QT (v = ch 384..575, v_mut = ch 960..1151) with transpose done in the LDS
// staging step -> no ktv kernel / Vt buffer.
// ---------------------------------------------------------------------------
__global__ __launch_bounds__(512, 4) void k5_mfma(
    const bf16* __restrict__ Mb, const bf16* __restrict__ QT,
    float* __restrict__ out)
{
    const int nt0 = blockIdx.x * 128;
    const int b   = blockIdx.z;
    const int tid = threadIdx.x;

    __shared__ short sM[192][72];
    __shared__ short sB[128][72];   // [n][d_local]

    const int wave = tid >> 6, lane = tid & 63;
    const int wm = (wave >> 2) * 96;   // 0 / 96
    const int wn = (wave & 3) * 32;    // 0 / 32 / 64 / 96
    const int lm = lane & 15, lq = lane >> 4;

    const bf16* Qb = QT + (size_t)b * TOT * NN;
    const bf16* Mp = Mb + (size_t)b * 192 * 384;

    float4_ acc[6][2];
    #pragma unroll
    for (int i = 0; i < 6; ++i)
        #pragma unroll
        for (int j = 0; j < 2; ++j)
            acc[i][j] = (float4_){0.f, 0.f, 0.f, 0.f};

    for (int kc = 0; kc < 384; kc += 64) {
        __syncthreads();
        // stage M tile: 192 rows x 64 k (1536 short8 granules, 3/thread)
        #pragma unroll
        for (int it = 0; it < 3; ++it) {
            const int id = it * 512 + tid;
            const int r = id >> 3, g = (id & 7) * 8;
            *(short8*)&sM[r][g] =
                *(const short8*)&Mp[(size_t)r * 384 + kc + g];
        }
        // stage V tile transposed from QT: channels chbase..chbase+63.
        const int chbase = (kc < 192) ? (384 + kc) : (960 + (kc - 192));
        #pragma unroll
        for (int it = 0; it < 2; ++it) {
            const int t = it * 512 + tid;
            const int d = t & 63, ng = t >> 6;
            short8 v = *(const short8*)
                &Qb[(size_t)(chbase + d) * NN + nt0 + ng * 8];
            #pragma unroll
            for (int j = 0; j < 8; ++j)
                sB[ng * 8 + j][d] = v[j];
        }
        __syncthreads();
        #pragma unroll
        for (int kk = 0; kk < 64; kk += 32) {
            short8 af[6], bfr[2];
            const int ko = kk + lq * 8;
            #pragma unroll
            for (int i = 0; i < 6; ++i)
                af[i] = *(const short8*)&sM[wm + i * 16 + lm][ko];
            #pragma unroll
            for (int j = 0; j < 2; ++j)
                bfr[j] = *(const short8*)&sB[wn + j * 16 + lm][ko];
            #pragma unroll
            for (int i = 0; i < 6; ++i)
                #pragma unroll
                for (int j = 0; j < 2; ++j)
                    acc[i][j] = __builtin_amdgcn_mfma_f32_16x16x32_bf16(
                        af[i], bfr[j], acc[i][j], 0, 0, 0);
        }
    }
    #pragma unroll
    for (int i = 0; i < 6; ++i)
        #pragma unroll
        for (int j = 0; j < 2; ++j) {
            const int n = nt0 + wn + j * 16 + lm;
            #pragma unroll
            for (int r = 0; r < 4; ++r) {
                const int m = wm + i * 16 + lq * 4 + r;
                out[((size_t)b * C_ + m) * NN + n] = acc[i][j][r];
            }
        }
}

// ---------------------------------------------------------------------------
extern "C" void kernel_launch(void* const* d_in, const int* in_sizes, int n_in,
                              void* d_out, int out_size, void* d_ws, size_t ws_size,
                              hipStream_t stream)
{
    const float* x     = (const float*)d_in[0];
    const float* xh    = (const float*)d_in[1];
    const float* qkvw  = (const float*)d_in[2];
    const float* qkvdw = (const float*)d_in[3];
    const float* qmw   = (const float*)d_in[4];
    const float* qmdw  = (const float*)d_in[5];
    const float* kvmw  = (const float*)d_in[6];
    const float* kvmdw = (const float*)d_in[7];
    const float* projw = (const float*)d_in[8];
    const float* tq    = (const float*)d_in[9];
    const float* tm    = (const float*)d_in[10];
    float* out = (float*)d_out;

    char* ws = (char*)d_ws;
    size_t off = 0;
    bf16*  QT = (bf16*)(ws + off);  off += (size_t)B_ * TOT * NN * 2;   // 151.0 MB
    bf16*  Y  = (bf16*)(ws + off);  off += (size_t)TOT * NN * 2;        // batch-loop scratch
    bf16*  Wb = (bf16*)(ws + off);  off += (size_t)TOT * C_ * 2;
    float* nrm = (float*)(ws + off); off += (size_t)B_ * 4 * 192 * 4;
    float* G   = (float*)(ws + off); off += (size_t)2 * B_ * HEADS * 48 * 48 * 4;
    bf16*  Mb  = (bf16*)(ws + off);  off += (size_t)B_ * 192 * 384 * 2;
    float* Gpart = (float*)(ws + off); off += (size_t)32 * 32 * 2304 * 4;  // 9.4 MB
    float* P = Gpart;  // softmax probs overlay Gpart (dead after kred/k4a)

    hipMemsetAsync(nrm, 0, (size_t)B_ * 4 * 192 * 4, stream);

    kprep_w<<<dim3((TOT * C_ + 255) / 256), 256, 0, stream>>>(qkvw, qmw, kvmw, Wb);

    for (int b = 0; b < B_; ++b) {
        kgemm<<<dim3(128, 18), 256, 0, stream>>>(Wb, x, xh, b, Y);
        kdw  <<<dim3(1152, 2), 256, 0, stream>>>(Y, qkvdw, qmdw, kvmdw, b, QT, nrm);
    }

    k3_mfma    <<<dim3(32, 8, B_), 256, 0, stream>>>(QT, Gpart);
    kred       <<<dim3((32 * 2304 + 255) / 256), 256, 0, stream>>>(Gpart, G);
    k4a_softmax<<<dim3(32, 4), 256, 0, stream>>>(G, nrm, tq, tm, P);
    k4b_fold   <<<dim3(32, 4), 256, 0, stream>>>(P, projw, Mb);
    k5_mfma    <<<dim3(128, 1, B_), 512, 0, stream>>>(Mb, QT, out);
}

// Round 10
// 388.979 us; speedup vs baseline: 1.0455x; 1.0455x over previous
//
#include <hip/hip_runtime.h>
#include <hip/hip_bf16.h>

typedef __hip_bfloat16 bf16;
using short8  = __attribute__((ext_vector_type(8))) short;
using float4_ = __attribute__((ext_vector_type(4))) float;

#define B_    4
#define C_    192
#define NN    16384   // 128*128
#define HEADS 4
#define CHD   48
#define TOT   1152    // 576 qkv + 192 q_mut + 384 kv_mut

__device__ __forceinline__ float b2f(bf16 v) { return __bfloat162float(v); }
__device__ __forceinline__ float s2f(short s) {
    return __uint_as_float(((unsigned)(unsigned short)s) << 16);
}

// ---------------------------------------------------------------------------
// kprep_w: concat+cast 1x1 weights -> Wb[1152][192] bf16.
// ---------------------------------------------------------------------------
__global__ __launch_bounds__(256) void kprep_w(
    const float* __restrict__ qkv_w, const float* __restrict__ qm_w,
    const float* __restrict__ kvm_w, bf16* __restrict__ Wb)
{
    int i = blockIdx.x * 256 + threadIdx.x;
    if (i >= TOT * C_) return;
    int r = i / C_, c = i % C_;
    float v = (r < 576) ? qkv_w[r * C_ + c]
            : (r < 768) ? qm_w[(r - 576) * C_ + c]
                        : kvm_w[(r - 768) * C_ + c];
    Wb[i] = __float2bfloat16(v);
}

// ---------------------------------------------------------------------------
// kprep_x: per-batch transpose+cast x / x_hidden -> Xt[2][16384][192] bf16.
// v2: 64x64 tile, float4 loads + short8 stores (16B both sides).
// Transpose amortized ONCE per batch, coalesced (round-9 lesson: doing it
// per-GEMM-tile with scattered rows is latency death).
// ---------------------------------------------------------------------------
__global__ __launch_bounds__(256) void kprep_x(
    const float* __restrict__ x, const float* __restrict__ xh,
    int b, bf16* __restrict__ Xt)
{
    const int src = blockIdx.z;
    const float* in = (src == 0 ? x : xh) + (size_t)b * C_ * NN;
    bf16* outp = Xt + (size_t)src * NN * C_;
    const int n0 = blockIdx.x * 64, c0 = blockIdx.y * 64;
    __shared__ float t[64][65];
    const int tid = threadIdx.x;

    // load: 64 c-rows x 16 float4 = 1024 tasks, 4/thread
    #pragma unroll
    for (int it = 0; it < 4; ++it) {
        const int id = it * 256 + tid;
        const int c = id >> 4, i4 = (id & 15) * 4;
        const float4_ v = *(const float4_*)&in[(size_t)(c0 + c) * NN + n0 + i4];
        t[c][i4 + 0] = v[0]; t[c][i4 + 1] = v[1];
        t[c][i4 + 2] = v[2]; t[c][i4 + 3] = v[3];
    }
    __syncthreads();

    // store: 64 n-rows x 8 short8 = 512 tasks, 2/thread
    #pragma unroll
    for (int it = 0; it < 2; ++it) {
        const int id = it * 256 + tid;
        const int n = id >> 3, j8 = (id & 7) * 8;
        short8 sv;
        #pragma unroll
        for (int k = 0; k < 8; ++k) {
            bf16 h = __float2bfloat16(t[j8 + k][n]);
            sv[k] = *reinterpret_cast<short*>(&h);
        }
        *(short8*)&outp[(size_t)(n0 + n) * C_ + c0 + j8] = sv;
    }
}

// ---------------------------------------------------------------------------
// kgemm: per-batch Y[1152][16384] = Wb[1152][192] x X[192][16384], bf16 MFMA.
// round-1 structure (proven optimum): 64x128 tile, A+B in LDS (27.6 KB),
// grid (128 nt, 18 mt), block 256 = 4 waves. Do NOT enlarge the tile
// (regressed rounds 2 & 7) or inline the transpose (regressed round 9).
// ---------------------------------------------------------------------------
__global__ __launch_bounds__(256) void kgemm(
    const bf16* __restrict__ Wb, const bf16* __restrict__ Xt,
    bf16* __restrict__ Y)
{
    const int nt0 = blockIdx.x * 128;
    const int mt0 = blockIdx.y * 64;
    const int tid = threadIdx.x;
    const bf16* Xs = Xt + (mt0 >= 768 ? (size_t)NN * C_ : 0);

    __shared__ short sA[64][72];
    __shared__ short sB[128][72];

    const int wave = tid >> 6, lane = tid & 63;
    const int mw = (wave & 1) * 32, nw = (wave >> 1) * 64;
    const int lm = lane & 15, lq = lane >> 4;

    float4_ acc[2][4];
    #pragma unroll
    for (int i = 0; i < 2; ++i)
        #pragma unroll
        for (int j = 0; j < 4; ++j)
            acc[i][j] = (float4_){0.f, 0.f, 0.f, 0.f};

    for (int kc = 0; kc < 192; kc += 64) {
        __syncthreads();
        {
            int r = tid >> 3, c8 = (tid & 7) * 8;
            #pragma unroll
            for (int it = 0; it < 2; ++it, r += 32)
                *(short8*)&sA[r][c8] =
                    *(const short8*)&Wb[(size_t)(mt0 + r) * C_ + kc + c8];
        }
        {
            int r = tid >> 3, c8 = (tid & 7) * 8;
            #pragma unroll
            for (int it = 0; it < 4; ++it, r += 32)
                *(short8*)&sB[r][c8] =
                    *(const short8*)&Xs[(size_t)(nt0 + r) * C_ + kc + c8];
        }
        __syncthreads();
        #pragma unroll
        for (int kk = 0; kk < 64; kk += 32) {
            short8 af[2], bfr[4];
            const int ko = kk + lq * 8;
            #pragma unroll
            for (int i = 0; i < 2; ++i)
                af[i] = *(const short8*)&sA[mw + i * 16 + lm][ko];
            #pragma unroll
            for (int j = 0; j < 4; ++j)
                bfr[j] = *(const short8*)&sB[nw + j * 16 + lm][ko];
            #pragma unroll
            for (int i = 0; i < 2; ++i)
                #pragma unroll
                for (int j = 0; j < 4; ++j)
                    acc[i][j] = __builtin_amdgcn_mfma_f32_16x16x32_bf16(
                        af[i], bfr[j], acc[i][j], 0, 0, 0);
        }
    }
    #pragma unroll
    for (int i = 0; i < 2; ++i)
        #pragma unroll
        for (int j = 0; j < 4; ++j) {
            const int n = nt0 + nw + j * 16 + lm;
            #pragma unroll
            for (int r = 0; r < 4; ++r) {
                const int m = mt0 + mw + i * 16 + lq * 4 + r;
                Y[(size_t)m * NN + n] = __float2bfloat16(acc[i][j][r]);
            }
        }
}

// ---------------------------------------------------------------------------
// kdw: per-batch depthwise 3x3 Y -> QT[b], register-resident row-sliding.
// v2: halo via lane shuffles (bit-exact, 3x fewer VMEM ops).
// ---------------------------------------------------------------------------
__device__ __forceinline__ void kdw_load_row(
    float* r, const bf16* __restrict__ Yc, int row, int x0, int lane)
{
    float f[8];
    if (row >= 0 && row <= 127) {
        short8 v = *(const short8*)(Yc + row * 128 + x0);
        #pragma unroll
        for (int i = 0; i < 8; ++i) f[i] = s2f(v[i]);
    } else {
        #pragma unroll
        for (int i = 0; i < 8; ++i) f[i] = 0.f;
    }
    const float lf = __shfl(f[7], lane - 1);
    const float rf = __shfl(f[0], lane + 1);
    r[0] = (x0 > 0)   ? lf : 0.f;
    r[9] = (x0 < 120) ? rf : 0.f;
    #pragma unroll
    for (int i = 0; i < 8; ++i) r[i + 1] = f[i];
}

__global__ __launch_bounds__(256) void kdw(
    const bf16* __restrict__ Y,
    const float* __restrict__ qkv_dw, const float* __restrict__ qm_dw,
    const float* __restrict__ kvm_dw, int b, bf16* __restrict__ QT,
    float* __restrict__ nrmsq)
{
    const int ch  = blockIdx.x;
    const int tid = threadIdx.x;
    const int tx = tid & 15, ty = tid >> 4;
    const int lane = tid & 63;
    const int x0 = tx * 8;
    const int y0 = blockIdx.y * 64 + ty * 4;

    const float* dwp = (ch < 576) ? qkv_dw + (size_t)ch * 9
                     : (ch < 768) ? qm_dw + (size_t)(ch - 576) * 9
                                  : kvm_dw + (size_t)(ch - 768) * 9;
    float w[9];
    #pragma unroll
    for (int i = 0; i < 9; ++i) w[i] = dwp[i];

    const bf16* Yc = Y + (size_t)ch * NN;
    bf16* qout = QT + ((size_t)b * TOT + ch) * NN;

    float r0[10], r1[10], r2[10];
    kdw_load_row(r0, Yc, y0 - 1, x0, lane);
    kdw_load_row(r1, Yc, y0,     x0, lane);

    float ssq = 0.f;
    #pragma unroll
    for (int yy = 0; yy < 4; ++yy) {
        kdw_load_row(r2, Yc, y0 + yy + 1, x0, lane);
        short8 sv;
        #pragma unroll
        for (int xx = 0; xx < 8; ++xx) {
            float s = w[0] * r0[xx] + w[1] * r0[xx + 1] + w[2] * r0[xx + 2]
                    + w[3] * r1[xx] + w[4] * r1[xx + 1] + w[5] * r1[xx + 2]
                    + w[6] * r2[xx] + w[7] * r2[xx + 1] + w[8] * r2[xx + 2];
            ssq += s * s;
            bf16 h = __float2bfloat16(s);
            sv[xx] = *reinterpret_cast<short*>(&h);
        }
        *(short8*)&qout[(size_t)(y0 + yy) * 128 + x0] = sv;
        #pragma unroll
        for (int i = 0; i < 10; ++i) { r0[i] = r1[i]; r1[i] = r2[i]; }
    }

    // fused sum-of-squares for norm classes q/k/q_mut/k_mut
    int cls = -1, ci = 0;
    if (ch < 192)                    { cls = 0; ci = ch; }
    else if (ch < 384)               { cls = 1; ci = ch - 192; }
    else if (ch >= 576 && ch < 768)  { cls = 2; ci = ch - 576; }
    else if (ch >= 768 && ch < 960)  { cls = 3; ci = ch - 768; }
    if (cls >= 0) {
        #pragma unroll
        for (int off = 32; off > 0; off >>= 1) ssq += __shfl_down(ssq, off);
        __shared__ float red[4];
        if ((tid & 63) == 0) red[tid >> 6] = ssq;
        __syncthreads();
        if (tid == 0)
            atomicAdd(&nrmsq[(b * 4 + cls) * 192 + ci],
                      red[0] + red[1] + red[2] + red[3]);
    }
}

// ---------------------------------------------------------------------------
// k3_mfma: Gram partials via MFMA, operands direct from global.
// grid (32 n-chunks of 512, 8 = t*4+h, 4 b), block 256 = 4 waves.
// ---------------------------------------------------------------------------
__global__ __launch_bounds__(256) void k3_mfma(
    const bf16* __restrict__ QT, float* __restrict__ Gpart)
{
    const int chunk = blockIdx.x;
    const int t = blockIdx.y >> 2, h = blockIdx.y & 3;
    const int b = blockIdx.z;
    const int qch = (t == 0 ? 0 : 576) + h * CHD;
    const int kch = (t == 0 ? 192 : 768) + h * CHD;
    const bf16* qp = QT + ((size_t)b * TOT + qch) * NN;
    const bf16* kp = QT + ((size_t)b * TOT + kch) * NN;

    const int tid = threadIdx.x;
    const int wave = tid >> 6, lane = tid & 63;
    const int lm = lane & 15, lq = lane >> 4;
    const int n0 = chunk * 512 + wave * 128;

    float4_ acc[3][3];
    #pragma unroll
    for (int i = 0; i < 3; ++i)
        #pragma unroll
        for (int j = 0; j < 3; ++j)
            acc[i][j] = (float4_){0.f, 0.f, 0.f, 0.f};

    #pragma unroll
    for (int kk = 0; kk < 128; kk += 32) {
        short8 af[3], bfr[3];
        const int ko = n0 + kk + lq * 8;
        #pragma unroll
        for (int i = 0; i < 3; ++i)
            af[i] = *(const short8*)&qp[(size_t)(i * 16 + lm) * NN + ko];
        #pragma unroll
        for (int j = 0; j < 3; ++j)
            bfr[j] = *(const short8*)&kp[(size_t)(j * 16 + lm) * NN + ko];
        #pragma unroll
        for (int i = 0; i < 3; ++i)
            #pragma unroll
            for (int j = 0; j < 3; ++j)
                acc[i][j] = __builtin_amdgcn_mfma_f32_16x16x32_bf16(
                    af[i], bfr[j], acc[i][j], 0, 0, 0);
    }

    __shared__ float sW[4][48 * 49];
    #pragma unroll
    for (int i = 0; i < 3; ++i)
        #pragma unroll
        for (int j = 0; j < 3; ++j)
            #pragma unroll
            for (int r = 0; r < 4; ++r)
                sW[wave][(i * 16 + lq * 4 + r) * 49 + j * 16 + lm] = acc[i][j][r];
    __syncthreads();

    const int gidx = ((t * 4 + b) * 4 + h);
    float* Gp = Gpart + ((size_t)gidx * 32 + chunk) * 2304;
    for (int idx = tid; idx < 2304; idx += 256) {
        const int c = idx / 48, d = idx % 48;
        Gp[idx] = sW[0][c * 49 + d] + sW[1][c * 49 + d]
                + sW[2][c * 49 + d] + sW[3][c * 49 + d];
    }
}

// ---------------------------------------------------------------------------
// ktail: fused kred + k4a + k4b. One block per gidx (32 total):
// 1) reduce Gpart[gidx][0..31][2304] -> sG (LDS), same ch-ascending order
// 2) wave-parallel softmax of 48 rows (12 rows/wave), same formula
// 3) fold proj -> Mb, same c-ascending 48-FMA loop
// All f32 math and orders identical to the 3 separate kernels -> bit-exact.
// Removes 2 launch gaps + G/P global round-trips.
// ---------------------------------------------------------------------------
__global__ __launch_bounds__(256) void ktail(
    const float* __restrict__ Gpart, const float* __restrict__ nrmsq,
    const float* __restrict__ proj_w, const float* __restrict__ tq,
    const float* __restrict__ tm, bf16* __restrict__ Mb)
{
    const int gidx = blockIdx.x;            // (t*4 + b)*4 + h
    const int h = gidx & 3, tb = gidx >> 2;
    const int b = tb & 3, t = tb >> 2;
    const int tid = threadIdx.x;

    __shared__ float sG[2304];       // reduced G
    __shared__ float sP[48][49];     // softmax probs
    __shared__ float sWall[192][49]; // proj slice [o][c]

    // 1) chunk reduction (order identical to kred)
    const float* p = Gpart + (size_t)gidx * 32 * 2304;
    for (int idx = tid; idx < 2304; idx += 256) {
        float s = 0.f;
        #pragma unroll
        for (int ch = 0; ch < 32; ++ch) s += p[(size_t)ch * 2304 + idx];
        sG[idx] = s;
    }
    // stage proj slice while reduction is in flight (independent)
    const int colb = t * 192 + h * 48;
    for (int idx = tid; idx < 192 * 48; idx += 256) {
        const int o = idx / 48, c = idx % 48;
        sWall[o][c] = proj_w[(size_t)o * 384 + colb + c];
    }
    __syncthreads();

    // 2) softmax rows: wave w handles rows w*12 .. w*12+11
    const int wave = tid >> 6, lane = tid & 63;
    const int clsq = (t == 0) ? 0 : 2, clsk = (t == 0) ? 1 : 3;
    const float tmp = (t == 0 ? tq[h] : tm[h]);
    float nk = 1.f;
    if (lane < 48)
        nk = fmaxf(sqrtf(fmaxf(nrmsq[(b * 4 + clsk) * 192 + h * 48 + lane], 0.f)),
                   1e-12f);
    const float sk = tmp / nk;
    for (int c = wave * 12; c < wave * 12 + 12; ++c) {
        const float nq =
            fmaxf(sqrtf(fmaxf(nrmsq[(b * 4 + clsq) * 192 + h * 48 + c], 0.f)),
                  1e-12f);
        float L = -1e30f;
        if (lane < 48) L = sG[c * 48 + lane] * sk / nq;
        float mx = L;
        #pragma unroll
        for (int off = 32; off > 0; off >>= 1)
            mx = fmaxf(mx, __shfl_xor(mx, off));
        float e = (lane < 48) ? expf(L - mx) : 0.f;
        float sum = e;
        #pragma unroll
        for (int off = 32; off > 0; off >>= 1)
            sum += __shfl_xor(sum, off);
        if (lane < 48) sP[c][lane] = e / sum;
    }
    __syncthreads();

    // 3) fold (order identical to k4b): 192*48 outputs, 36/thread
    for (int idx = tid; idx < 192 * 48; idx += 256) {
        const int o = idx / 48, d = idx % 48;
        float s = 0.f;
        #pragma unroll
        for (int c = 0; c < 48; ++c) s += sWall[o][c] * sP[c][d];
        Mb[((size_t)b * 192 + o) * 384 + colb + d] = __float2bfloat16(s);
    }
}

// ---------------------------------------------------------------------------
// k5_mfma: out[b][192][16384] = Mb[b][192][384] x V, V taken DIRECTLY from
// QT (v = ch 384..575, v_mut = ch 960..1151) with transpose done in the LDS
// staging step -> no ktv kernel / Vt buffer.
// ---------------------------------------------------------------------------
__global__ __launch_bounds__(512, 4) void k5_mfma(
    const bf16* __restrict__ Mb, const bf16* __restrict__ QT,
    float* __restrict__ out)
{
    const int nt0 = blockIdx.x * 128;
    const int b   = blockIdx.z;
    const int tid = threadIdx.x;

    __shared__ short sM[192][72];
    __shared__ short sB[128][72];   // [n][d_local]

    const int wave = tid >> 6, lane = tid & 63;
    const int wm = (wave >> 2) * 96;   // 0 / 96
    const int wn = (wave & 3) * 32;    // 0 / 32 / 64 / 96
    const int lm = lane & 15, lq = lane >> 4;

    const bf16* Qb = QT + (size_t)b * TOT * NN;
    const bf16* Mp = Mb + (size_t)b * 192 * 384;

    float4_ acc[6][2];
    #pragma unroll
    for (int i = 0; i < 6; ++i)
        #pragma unroll
        for (int j = 0; j < 2; ++j)
            acc[i][j] = (float4_){0.f, 0.f, 0.f, 0.f};

    for (int kc = 0; kc < 384; kc += 64) {
        __syncthreads();
        // stage M tile: 192 rows x 64 k (1536 short8 granules, 3/thread)
        #pragma unroll
        for (int it = 0; it < 3; ++it) {
            const int id = it * 512 + tid;
            const int r = id >> 3, g = (id & 7) * 8;
            *(short8*)&sM[r][g] =
                *(const short8*)&Mp[(size_t)r * 384 + kc + g];
        }
        // stage V tile transposed from QT: channels chbase..chbase+63.
        const int chbase = (kc < 192) ? (384 + kc) : (960 + (kc - 192));
        #pragma unroll
        for (int it = 0; it < 2; ++it) {
            const int t = it * 512 + tid;
            const int d = t & 63, ng = t >> 6;
            short8 v = *(const short8*)
                &Qb[(size_t)(chbase + d) * NN + nt0 + ng * 8];
            #pragma unroll
            for (int j = 0; j < 8; ++j)
                sB[ng * 8 + j][d] = v[j];
        }
        __syncthreads();
        #pragma unroll
        for (int kk = 0; kk < 64; kk += 32) {
            short8 af[6], bfr[2];
            const int ko = kk + lq * 8;
            #pragma unroll
            for (int i = 0; i < 6; ++i)
                af[i] = *(const short8*)&sM[wm + i * 16 + lm][ko];
            #pragma unroll
            for (int j = 0; j < 2; ++j)
                bfr[j] = *(const short8*)&sB[wn + j * 16 + lm][ko];
            #pragma unroll
            for (int i = 0; i < 6; ++i)
                #pragma unroll
                for (int j = 0; j < 2; ++j)
                    acc[i][j] = __builtin_amdgcn_mfma_f32_16x16x32_bf16(
                        af[i], bfr[j], acc[i][j], 0, 0, 0);
        }
    }
    #pragma unroll
    for (int i = 0; i < 6; ++i)
        #pragma unroll
        for (int j = 0; j < 2; ++j) {
            const int n = nt0 + wn + j * 16 + lm;
            #pragma unroll
            for (int r = 0; r < 4; ++r) {
                const int m = wm + i * 16 + lq * 4 + r;
                out[((size_t)b * C_ + m) * NN + n] = acc[i][j][r];
            }
        }
}

// ---------------------------------------------------------------------------
extern "C" void kernel_launch(void* const* d_in, const int* in_sizes, int n_in,
                              void* d_out, int out_size, void* d_ws, size_t ws_size,
                              hipStream_t stream)
{
    const float* x     = (const float*)d_in[0];
    const float* xh    = (const float*)d_in[1];
    const float* qkvw  = (const float*)d_in[2];
    const float* qkvdw = (const float*)d_in[3];
    const float* qmw   = (const float*)d_in[4];
    const float* qmdw  = (const float*)d_in[5];
    const float* kvmw  = (const float*)d_in[6];
    const float* kvmdw = (const float*)d_in[7];
    const float* projw = (const float*)d_in[8];
    const float* tq    = (const float*)d_in[9];
    const float* tm    = (const float*)d_in[10];
    float* out = (float*)d_out;

    char* ws = (char*)d_ws;
    size_t off = 0;
    bf16*  QT = (bf16*)(ws + off);  off += (size_t)B_ * TOT * NN * 2;   // 151.0 MB
    bf16*  Y  = (bf16*)(ws + off);  off += (size_t)TOT * NN * 2;        // batch-loop scratch
    bf16*  Xt = (bf16*)(ws + off);  off += (size_t)2 * NN * C_ * 2;
    bf16*  Wb = (bf16*)(ws + off);  off += (size_t)TOT * C_ * 2;
    float* nrm = (float*)(ws + off); off += (size_t)B_ * 4 * 192 * 4;
    bf16*  Mb  = (bf16*)(ws + off);  off += (size_t)B_ * 192 * 384 * 2;
    float* Gpart = (float*)(ws + off); off += (size_t)32 * 32 * 2304 * 4;  // 9.4 MB

    hipMemsetAsync(nrm, 0, (size_t)B_ * 4 * 192 * 4, stream);

    kprep_w<<<dim3((TOT * C_ + 255) / 256), 256, 0, stream>>>(qkvw, qmw, kvmw, Wb);

    for (int b = 0; b < B_; ++b) {
        kprep_x<<<dim3(256, 3, 2), 256, 0, stream>>>(x, xh, b, Xt);
        kgemm  <<<dim3(128, 18), 256, 0, stream>>>(Wb, Xt, Y);
        kdw    <<<dim3(1152, 2), 256, 0, stream>>>(Y, qkvdw, qmdw, kvmdw, b, QT, nrm);
    }

    k3_mfma<<<dim3(32, 8, B_), 256, 0, stream>>>(QT, Gpart);
    ktail  <<<dim3(32), 256, 0, stream>>>(Gpart, nrm, projw, tq, tm, Mb);
    k5_mfma<<<dim3(128, 1, B_), 512, 0, stream>>>(Mb, QT, out);
}

// Round 11
// 358.194 us; speedup vs baseline: 1.1353x; 1.0859x over previous
//
#include <hip/hip_runtime.h>
#include <hip/hip_bf16.h>

typedef __hip_bfloat16 bf16;
using short8  = __attribute__((ext_vector_type(8))) short;
using float4_ = __attribute__((ext_vector_type(4))) float;

#define B_    4
#define C_    192
#define NN    16384   // 128*128
#define HEADS 4
#define CHD   48
#define TOT   1152    // 576 qkv + 192 q_mut + 384 kv_mut

__device__ __forceinline__ float b2f(bf16 v) { return __bfloat162float(v); }
__device__ __forceinline__ float s2f(short s) {
    return __uint_as_float(((unsigned)(unsigned short)s) << 16);
}

// ---------------------------------------------------------------------------
// kprep_w: concat+cast 1x1 weights -> Wb[1152][192] bf16.
// ---------------------------------------------------------------------------
__global__ __launch_bounds__(256) void kprep_w(
    const float* __restrict__ qkv_w, const float* __restrict__ qm_w,
    const float* __restrict__ kvm_w, bf16* __restrict__ Wb)
{
    int i = blockIdx.x * 256 + threadIdx.x;
    if (i >= TOT * C_) return;
    int r = i / C_, c = i % C_;
    float v = (r < 576) ? qkv_w[r * C_ + c]
            : (r < 768) ? qm_w[(r - 576) * C_ + c]
                        : kvm_w[(r - 768) * C_ + c];
    Wb[i] = __float2bfloat16(v);
}

// ---------------------------------------------------------------------------
// kprep_x: per-batch transpose+cast x / x_hidden -> Xt[2][16384][192] bf16.
// v2: 64x64 tile, float4 loads + short8 stores (16B both sides).
// Transpose amortized ONCE per batch, coalesced.
// ---------------------------------------------------------------------------
__global__ __launch_bounds__(256) void kprep_x(
    const float* __restrict__ x, const float* __restrict__ xh,
    int b, bf16* __restrict__ Xt)
{
    const int src = blockIdx.z;
    const float* in = (src == 0 ? x : xh) + (size_t)b * C_ * NN;
    bf16* outp = Xt + (size_t)src * NN * C_;
    const int n0 = blockIdx.x * 64, c0 = blockIdx.y * 64;
    __shared__ float t[64][65];
    const int tid = threadIdx.x;

    // load: 64 c-rows x 16 float4 = 1024 tasks, 4/thread
    #pragma unroll
    for (int it = 0; it < 4; ++it) {
        const int id = it * 256 + tid;
        const int c = id >> 4, i4 = (id & 15) * 4;
        const float4_ v = *(const float4_*)&in[(size_t)(c0 + c) * NN + n0 + i4];
        t[c][i4 + 0] = v[0]; t[c][i4 + 1] = v[1];
        t[c][i4 + 2] = v[2]; t[c][i4 + 3] = v[3];
    }
    __syncthreads();

    // store: 64 n-rows x 8 short8 = 512 tasks, 2/thread
    #pragma unroll
    for (int it = 0; it < 2; ++it) {
        const int id = it * 256 + tid;
        const int n = id >> 3, j8 = (id & 7) * 8;
        short8 sv;
        #pragma unroll
        for (int k = 0; k < 8; ++k) {
            bf16 h = __float2bfloat16(t[j8 + k][n]);
            sv[k] = *reinterpret_cast<short*>(&h);
        }
        *(short8*)&outp[(size_t)(n0 + n) * C_ + c0 + j8] = sv;
    }
}

// ---------------------------------------------------------------------------
// kgemm: per-batch Y[1152][16384] = Wb[1152][192] x X[192][16384], bf16 MFMA.
// round-1 structure (proven optimum): 64x128 tile, A+B in LDS (27.6 KB),
// grid (128 nt, 18 mt), block 256 = 4 waves. Do NOT enlarge the tile
// (regressed rounds 2 & 7) or inline the transpose (regressed round 9).
// ---------------------------------------------------------------------------
__global__ __launch_bounds__(256) void kgemm(
    const bf16* __restrict__ Wb, const bf16* __restrict__ Xt,
    bf16* __restrict__ Y)
{
    const int nt0 = blockIdx.x * 128;
    const int mt0 = blockIdx.y * 64;
    const int tid = threadIdx.x;
    const bf16* Xs = Xt + (mt0 >= 768 ? (size_t)NN * C_ : 0);

    __shared__ short sA[64][72];
    __shared__ short sB[128][72];

    const int wave = tid >> 6, lane = tid & 63;
    const int mw = (wave & 1) * 32, nw = (wave >> 1) * 64;
    const int lm = lane & 15, lq = lane >> 4;

    float4_ acc[2][4];
    #pragma unroll
    for (int i = 0; i < 2; ++i)
        #pragma unroll
        for (int j = 0; j < 4; ++j)
            acc[i][j] = (float4_){0.f, 0.f, 0.f, 0.f};

    for (int kc = 0; kc < 192; kc += 64) {
        __syncthreads();
        {
            int r = tid >> 3, c8 = (tid & 7) * 8;
            #pragma unroll
            for (int it = 0; it < 2; ++it, r += 32)
                *(short8*)&sA[r][c8] =
                    *(const short8*)&Wb[(size_t)(mt0 + r) * C_ + kc + c8];
        }
        {
            int r = tid >> 3, c8 = (tid & 7) * 8;
            #pragma unroll
            for (int it = 0; it < 4; ++it, r += 32)
                *(short8*)&sB[r][c8] =
                    *(const short8*)&Xs[(size_t)(nt0 + r) * C_ + kc + c8];
        }
        __syncthreads();
        #pragma unroll
        for (int kk = 0; kk < 64; kk += 32) {
            short8 af[2], bfr[4];
            const int ko = kk + lq * 8;
            #pragma unroll
            for (int i = 0; i < 2; ++i)
                af[i] = *(const short8*)&sA[mw + i * 16 + lm][ko];
            #pragma unroll
            for (int j = 0; j < 4; ++j)
                bfr[j] = *(const short8*)&sB[nw + j * 16 + lm][ko];
            #pragma unroll
            for (int i = 0; i < 2; ++i)
                #pragma unroll
                for (int j = 0; j < 4; ++j)
                    acc[i][j] = __builtin_amdgcn_mfma_f32_16x16x32_bf16(
                        af[i], bfr[j], acc[i][j], 0, 0, 0);
        }
    }
    #pragma unroll
    for (int i = 0; i < 2; ++i)
        #pragma unroll
        for (int j = 0; j < 4; ++j) {
            const int n = nt0 + nw + j * 16 + lm;
            #pragma unroll
            for (int r = 0; r < 4; ++r) {
                const int m = mt0 + mw + i * 16 + lq * 4 + r;
                Y[(size_t)m * NN + n] = __float2bfloat16(acc[i][j][r]);
            }
        }
}

// ---------------------------------------------------------------------------
// kdw: per-batch depthwise 3x3 Y -> QT[b], register-resident row-sliding.
// v2: halo via lane shuffles (bit-exact, 3x fewer VMEM ops).
// ---------------------------------------------------------------------------
__device__ __forceinline__ void kdw_load_row(
    float* r, const bf16* __restrict__ Yc, int row, int x0, int lane)
{
    float f[8];
    if (row >= 0 && row <= 127) {
        short8 v = *(const short8*)(Yc + row * 128 + x0);
        #pragma unroll
        for (int i = 0; i < 8; ++i) f[i] = s2f(v[i]);
    } else {
        #pragma unroll
        for (int i = 0; i < 8; ++i) f[i] = 0.f;
    }
    const float lf = __shfl(f[7], lane - 1);
    const float rf = __shfl(f[0], lane + 1);
    r[0] = (x0 > 0)   ? lf : 0.f;
    r[9] = (x0 < 120) ? rf : 0.f;
    #pragma unroll
    for (int i = 0; i < 8; ++i) r[i + 1] = f[i];
}

__global__ __launch_bounds__(256) void kdw(
    const bf16* __restrict__ Y,
    const float* __restrict__ qkv_dw, const float* __restrict__ qm_dw,
    const float* __restrict__ kvm_dw, int b, bf16* __restrict__ QT,
    float* __restrict__ nrmsq)
{
    const int ch  = blockIdx.x;
    const int tid = threadIdx.x;
    const int tx = tid & 15, ty = tid >> 4;
    const int lane = tid & 63;
    const int x0 = tx * 8;
    const int y0 = blockIdx.y * 64 + ty * 4;

    const float* dwp = (ch < 576) ? qkv_dw + (size_t)ch * 9
                     : (ch < 768) ? qm_dw + (size_t)(ch - 576) * 9
                                  : kvm_dw + (size_t)(ch - 768) * 9;
    float w[9];
    #pragma unroll
    for (int i = 0; i < 9; ++i) w[i] = dwp[i];

    const bf16* Yc = Y + (size_t)ch * NN;
    bf16* qout = QT + ((size_t)b * TOT + ch) * NN;

    float r0[10], r1[10], r2[10];
    kdw_load_row(r0, Yc, y0 - 1, x0, lane);
    kdw_load_row(r1, Yc, y0,     x0, lane);

    float ssq = 0.f;
    #pragma unroll
    for (int yy = 0; yy < 4; ++yy) {
        kdw_load_row(r2, Yc, y0 + yy + 1, x0, lane);
        short8 sv;
        #pragma unroll
        for (int xx = 0; xx < 8; ++xx) {
            float s = w[0] * r0[xx] + w[1] * r0[xx + 1] + w[2] * r0[xx + 2]
                    + w[3] * r1[xx] + w[4] * r1[xx + 1] + w[5] * r1[xx + 2]
                    + w[6] * r2[xx] + w[7] * r2[xx + 1] + w[8] * r2[xx + 2];
            ssq += s * s;
            bf16 h = __float2bfloat16(s);
            sv[xx] = *reinterpret_cast<short*>(&h);
        }
        *(short8*)&qout[(size_t)(y0 + yy) * 128 + x0] = sv;
        #pragma unroll
        for (int i = 0; i < 10; ++i) { r0[i] = r1[i]; r1[i] = r2[i]; }
    }

    // fused sum-of-squares for norm classes q/k/q_mut/k_mut
    int cls = -1, ci = 0;
    if (ch < 192)                    { cls = 0; ci = ch; }
    else if (ch < 384)               { cls = 1; ci = ch - 192; }
    else if (ch >= 576 && ch < 768)  { cls = 2; ci = ch - 576; }
    else if (ch >= 768 && ch < 960)  { cls = 3; ci = ch - 768; }
    if (cls >= 0) {
        #pragma unroll
        for (int off = 32; off > 0; off >>= 1) ssq += __shfl_down(ssq, off);
        __shared__ float red[4];
        if ((tid & 63) == 0) red[tid >> 6] = ssq;
        __syncthreads();
        if (tid == 0)
            atomicAdd(&nrmsq[(b * 4 + cls) * 192 + ci],
                      red[0] + red[1] + red[2] + red[3]);
    }
}

// ---------------------------------------------------------------------------
// k3_mfma: Gram partials via MFMA, operands direct from global.
// grid (32 n-chunks of 512, 8 = t*4+h, 4 b), block 256 = 4 waves.
// ---------------------------------------------------------------------------
__global__ __launch_bounds__(256) void k3_mfma(
    const bf16* __restrict__ QT, float* __restrict__ Gpart)
{
    const int chunk = blockIdx.x;
    const int t = blockIdx.y >> 2, h = blockIdx.y & 3;
    const int b = blockIdx.z;
    const int qch = (t == 0 ? 0 : 576) + h * CHD;
    const int kch = (t == 0 ? 192 : 768) + h * CHD;
    const bf16* qp = QT + ((size_t)b * TOT + qch) * NN;
    const bf16* kp = QT + ((size_t)b * TOT + kch) * NN;

    const int tid = threadIdx.x;
    const int wave = tid >> 6, lane = tid & 63;
    const int lm = lane & 15, lq = lane >> 4;
    const int n0 = chunk * 512 + wave * 128;

    float4_ acc[3][3];
    #pragma unroll
    for (int i = 0; i < 3; ++i)
        #pragma unroll
        for (int j = 0; j < 3; ++j)
            acc[i][j] = (float4_){0.f, 0.f, 0.f, 0.f};

    #pragma unroll
    for (int kk = 0; kk < 128; kk += 32) {
        short8 af[3], bfr[3];
        const int ko = n0 + kk + lq * 8;
        #pragma unroll
        for (int i = 0; i < 3; ++i)
            af[i] = *(const short8*)&qp[(size_t)(i * 16 + lm) * NN + ko];
        #pragma unroll
        for (int j = 0; j < 3; ++j)
            bfr[j] = *(const short8*)&kp[(size_t)(j * 16 + lm) * NN + ko];
        #pragma unroll
        for (int i = 0; i < 3; ++i)
            #pragma unroll
            for (int j = 0; j < 3; ++j)
                acc[i][j] = __builtin_amdgcn_mfma_f32_16x16x32_bf16(
                    af[i], bfr[j], acc[i][j], 0, 0, 0);
    }

    __shared__ float sW[4][48 * 49];
    #pragma unroll
    for (int i = 0; i < 3; ++i)
        #pragma unroll
        for (int j = 0; j < 3; ++j)
            #pragma unroll
            for (int r = 0; r < 4; ++r)
                sW[wave][(i * 16 + lq * 4 + r) * 49 + j * 16 + lm] = acc[i][j][r];
    __syncthreads();

    const int gidx = ((t * 4 + b) * 4 + h);
    float* Gp = Gpart + ((size_t)gidx * 32 + chunk) * 2304;
    for (int idx = tid; idx < 2304; idx += 256) {
        const int c = idx / 48, d = idx % 48;
        Gp[idx] = sW[0][c * 49 + d] + sW[1][c * 49 + d]
                + sW[2][c * 49 + d] + sW[3][c * 49 + d];
    }
}

// ---------------------------------------------------------------------------
// kred: G[gidx][2304] = sum over 32 chunks of Gpart[gidx][chunk][2304].
// 288 blocks — keep the tail parallel (round-10 lesson: 32-block fusion
// was latency death; launch gaps are cheaper than lost TLP).
// ---------------------------------------------------------------------------
__global__ __launch_bounds__(256) void kred(
    const float* __restrict__ Gpart, float* __restrict__ G)
{
    const int idx = blockIdx.x * 256 + threadIdx.x;
    if (idx >= 32 * 2304) return;
    const int g = idx / 2304, i = idx % 2304;
    const float* p = Gpart + (size_t)g * 32 * 2304 + i;
    float s = 0.f;
    #pragma unroll
    for (int ch = 0; ch < 32; ++ch) s += p[(size_t)ch * 2304];
    G[(size_t)g * 2304 + i] = s;
}

// ---------------------------------------------------------------------------
// k4a_softmax: wave-per-row softmax of the 32 48x48 logit matrices.
// ---------------------------------------------------------------------------
__global__ __launch_bounds__(256) void k4a_softmax(
    const float* __restrict__ G, const float* __restrict__ nrmsq,
    const float* __restrict__ tq, const float* __restrict__ tm,
    float* __restrict__ P)
{
    const int gidx = blockIdx.x;            // (t*4 + b)*4 + h
    const int h = gidx & 3, tb = gidx >> 2;
    const int b = tb & 3, t = tb >> 2;
    const float* Gp = G + (size_t)gidx * 2304;
    float* Pp = P + (size_t)gidx * 2304;

    const int tid = threadIdx.x;
    const int wave = tid >> 6, lane = tid & 63;
    const int clsq = (t == 0) ? 0 : 2, clsk = (t == 0) ? 1 : 3;
    const float tmp = (t == 0 ? tq[h] : tm[h]);

    float nk = 1.f;
    if (lane < 48)
        nk = fmaxf(sqrtf(fmaxf(nrmsq[(b * 4 + clsk) * 192 + h * 48 + lane], 0.f)),
                   1e-12f);
    const float sk = tmp / nk;   // per-lane (per-d) scale

    const int c0 = blockIdx.y * 12 + wave * 3;
    #pragma unroll
    for (int cc = 0; cc < 3; ++cc) {
        const int c = c0 + cc;
        const float nq =
            fmaxf(sqrtf(fmaxf(nrmsq[(b * 4 + clsq) * 192 + h * 48 + c], 0.f)),
                  1e-12f);
        float L = -1e30f;
        if (lane < 48) L = Gp[c * 48 + lane] * sk / nq;
        float mx = L;
        #pragma unroll
        for (int off = 32; off > 0; off >>= 1)
            mx = fmaxf(mx, __shfl_xor(mx, off));
        float e = (lane < 48) ? expf(L - mx) : 0.f;
        float sum = e;
        #pragma unroll
        for (int off = 32; off > 0; off >>= 1)
            sum += __shfl_xor(sum, off);
        if (lane < 48) Pp[c * 48 + lane] = e / sum;
    }
}

// ---------------------------------------------------------------------------
// k4b_fold: Mb[b][o][t*192+h*48+d] = sum_c proj[o][t*192+h*48+c] * P[c][d].
// ---------------------------------------------------------------------------
__global__ __launch_bounds__(256) void k4b_fold(
    const float* __restrict__ P, const float* __restrict__ proj_w,
    bf16* __restrict__ Mb)
{
    const int gidx = blockIdx.x;
    const int h = gidx & 3, tb = gidx >> 2;
    const int b = tb & 3, t = tb >> 2;
    const int o0 = blockIdx.y * 48;
    const int colb = t * 192 + h * 48;

    __shared__ float sP[48][49];   // sP[c][d]
    __shared__ float sW[48][49];   // sW[o_local][c]
    const int tid = threadIdx.x;
    const float* Pp = P + (size_t)gidx * 2304;

    for (int idx = tid; idx < 2304; idx += 256) {
        const int r = idx / 48, q = idx % 48;
        sP[r][q] = Pp[idx];
        sW[r][q] = proj_w[(size_t)(o0 + r) * 384 + colb + q];
    }
    __syncthreads();

    for (int idx = tid; idx < 2304; idx += 256) {
        const int o = idx / 48, d = idx % 48;
        float s = 0.f;
        #pragma unroll
        for (int c = 0; c < 48; ++c) s += sW[o][c] * sP[c][d];
        Mb[((size_t)b * 192 + o0 + o) * 384 + colb + d] = __float2bfloat16(s);
    }
}

// ---------------------------------------------------------------------------
// k5_mfma: out[b][192][16384] = Mb[b][192][384] x V, V taken DIRECTLY from
// QT (v = ch 384..575, v_mut = ch 960..1151) with transpose done in the LDS
// staging step -> no ktv kernel / Vt buffer.
// ---------------------------------------------------------------------------
__global__ __launch_bounds__(512, 4) void k5_mfma(
    const bf16* __restrict__ Mb, const bf16* __restrict__ QT,
    float* __restrict__ out)
{
    const int nt0 = blockIdx.x * 128;
    const int b   = blockIdx.z;
    const int tid = threadIdx.x;

    __shared__ short sM[192][72];
    __shared__ short sB[128][72];   // [n][d_local]

    const int wave = tid >> 6, lane = tid & 63;
    const int wm = (wave >> 2) * 96;   // 0 / 96
    const int wn = (wave & 3) * 32;    // 0 / 32 / 64 / 96
    const int lm = lane & 15, lq = lane >> 4;

    const bf16* Qb = QT + (size_t)b * TOT * NN;
    const bf16* Mp = Mb + (size_t)b * 192 * 384;

    float4_ acc[6][2];
    #pragma unroll
    for (int i = 0; i < 6; ++i)
        #pragma unroll
        for (int j = 0; j < 2; ++j)
            acc[i][j] = (float4_){0.f, 0.f, 0.f, 0.f};

    for (int kc = 0; kc < 384; kc += 64) {
        __syncthreads();
        // stage M tile: 192 rows x 64 k (1536 short8 granules, 3/thread)
        #pragma unroll
        for (int it = 0; it < 3; ++it) {
            const int id = it * 512 + tid;
            const int r = id >> 3, g = (id & 7) * 8;
            *(short8*)&sM[r][g] =
                *(const short8*)&Mp[(size_t)r * 384 + kc + g];
        }
        // stage V tile transposed from QT: channels chbase..chbase+63.
        const int chbase = (kc < 192) ? (384 + kc) : (960 + (kc - 192));
        #pragma unroll
        for (int it = 0; it < 2; ++it) {
            const int t = it * 512 + tid;
            const int d = t & 63, ng = t >> 6;
            short8 v = *(const short8*)
                &Qb[(size_t)(chbase + d) * NN + nt0 + ng * 8];
            #pragma unroll
            for (int j = 0; j < 8; ++j)
                sB[ng * 8 + j][d] = v[j];
        }
        __syncthreads();
        #pragma unroll
        for (int kk = 0; kk < 64; kk += 32) {
            short8 af[6], bfr[2];
            const int ko = kk + lq * 8;
            #pragma unroll
            for (int i = 0; i < 6; ++i)
                af[i] = *(const short8*)&sM[wm + i * 16 + lm][ko];
            #pragma unroll
            for (int j = 0; j < 2; ++j)
                bfr[j] = *(const short8*)&sB[wn + j * 16 + lm][ko];
            #pragma unroll
            for (int i = 0; i < 6; ++i)
                #pragma unroll
                for (int j = 0; j < 2; ++j)
                    acc[i][j] = __builtin_amdgcn_mfma_f32_16x16x32_bf16(
                        af[i], bfr[j], acc[i][j], 0, 0, 0);
        }
    }
    #pragma unroll
    for (int i = 0; i < 6; ++i)
        #pragma unroll
        for (int j = 0; j < 2; ++j) {
            const int n = nt0 + wn + j * 16 + lm;
            #pragma unroll
            for (int r = 0; r < 4; ++r) {
                const int m = wm + i * 16 + lq * 4 + r;
                out[((size_t)b * C_ + m) * NN + n] = acc[i][j][r];
            }
        }
}

// ---------------------------------------------------------------------------
extern "C" void kernel_launch(void* const* d_in, const int* in_sizes, int n_in,
                              void* d_out, int out_size, void* d_ws, size_t ws_size,
                              hipStream_t stream)
{
    const float* x     = (const float*)d_in[0];
    const float* xh    = (const float*)d_in[1];
    const float* qkvw  = (const float*)d_in[2];
    const float* qkvdw = (const float*)d_in[3];
    const float* qmw   = (const float*)d_in[4];
    const float* qmdw  = (const float*)d_in[5];
    const float* kvmw  = (const float*)d_in[6];
    const float* kvmdw = (const float*)d_in[7];
    const float* projw = (const float*)d_in[8];
    const float* tq    = (const float*)d_in[9];
    const float* tm    = (const float*)d_in[10];
    float* out = (float*)d_out;

    char* ws = (char*)d_ws;
    size_t off = 0;
    bf16*  QT = (bf16*)(ws + off);  off += (size_t)B_ * TOT * NN * 2;   // 151.0 MB
    bf16*  Y  = (bf16*)(ws + off);  off += (size_t)TOT * NN * 2;        // batch-loop scratch
    bf16*  Xt = (bf16*)(ws + off);  off += (size_t)2 * NN * C_ * 2;
    bf16*  Wb = (bf16*)(ws + off);  off += (size_t)TOT * C_ * 2;
    float* nrm = (float*)(ws + off); off += (size_t)B_ * 4 * 192 * 4;
    float* G   = (float*)(ws + off); off += (size_t)2 * B_ * HEADS * 48 * 48 * 4;
    bf16*  Mb  = (bf16*)(ws + off);  off += (size_t)B_ * 192 * 384 * 2;
    float* Gpart = (float*)(ws + off); off += (size_t)32 * 32 * 2304 * 4;  // 9.4 MB
    float* P = Gpart;  // softmax probs overlay Gpart (dead after kred/k4a)

    hipMemsetAsync(nrm, 0, (size_t)B_ * 4 * 192 * 4, stream);

    kprep_w<<<dim3((TOT * C_ + 255) / 256), 256, 0, stream>>>(qkvw, qmw, kvmw, Wb);

    for (int b = 0; b < B_; ++b) {
        kprep_x<<<dim3(256, 3, 2), 256, 0, stream>>>(x, xh, b, Xt);
        kgemm  <<<dim3(128, 18), 256, 0, stream>>>(Wb, Xt, Y);
        kdw    <<<dim3(1152, 2), 256, 0, stream>>>(Y, qkvdw, qmdw, kvmdw, b, QT, nrm);
    }

    k3_mfma    <<<dim3(32, 8, B_), 256, 0, stream>>>(QT, Gpart);
    kred       <<<dim3((32 * 2304 + 255) / 256), 256, 0, stream>>>(Gpart, G);
    k4a_softmax<<<dim3(32, 4), 256, 0, stream>>>(G, nrm, tq, tm, P);
    k4b_fold   <<<dim3(32, 4), 256, 0, stream>>>(P, projw, Mb);
    k5_mfma    <<<dim3(128, 1, B_), 512, 0, stream>>>(Mb, QT, out);
}

// Round 12
// 332.172 us; speedup vs baseline: 1.2242x; 1.0783x over previous
//
#include <hip/hip_runtime.h>
#include <hip/hip_bf16.h>

typedef __hip_bfloat16 bf16;
using short8  = __attribute__((ext_vector_type(8))) short;
using float4_ = __attribute__((ext_vector_type(4))) float;

#define B_    4
#define C_    192
#define NN    16384   // 128*128
#define HEADS 4
#define CHD   48
#define TOT   1152    // 576 qkv + 192 q_mut + 384 kv_mut

__device__ __forceinline__ float b2f(bf16 v) { return __bfloat162float(v); }
__device__ __forceinline__ float s2f(short s) {
    return __uint_as_float(((unsigned)(unsigned short)s) << 16);
}

// ---------------------------------------------------------------------------
// kprep_w: concat+cast 1x1 weights -> Wb[1152][192] bf16.
// ---------------------------------------------------------------------------
__global__ __launch_bounds__(256) void kprep_w(
    const float* __restrict__ qkv_w, const float* __restrict__ qm_w,
    const float* __restrict__ kvm_w, bf16* __restrict__ Wb)
{
    int i = blockIdx.x * 256 + threadIdx.x;
    if (i >= TOT * C_) return;
    int r = i / C_, c = i % C_;
    float v = (r < 576) ? qkv_w[r * C_ + c]
            : (r < 768) ? qm_w[(r - 576) * C_ + c]
                        : kvm_w[(r - 768) * C_ + c];
    Wb[i] = __float2bfloat16(v);
}

// ---------------------------------------------------------------------------
// kprep_x: transpose+cast x / x_hidden -> Xt[pb][2][16384][192] bf16.
// v3: batch-pair z (pb = z>>1, src = z&1). 64x64 tile, float4 loads +
// short8 stores. Per-element math unchanged -> bit-exact.
// ---------------------------------------------------------------------------
__global__ __launch_bounds__(256) void kprep_x(
    const float* __restrict__ x, const float* __restrict__ xh,
    int p, bf16* __restrict__ Xt)
{
    const int pb = blockIdx.z >> 1, src = blockIdx.z & 1;
    const int b = p * 2 + pb;
    const float* in = (src == 0 ? x : xh) + (size_t)b * C_ * NN;
    bf16* outp = Xt + ((size_t)pb * 2 + src) * NN * C_;
    const int n0 = blockIdx.x * 64, c0 = blockIdx.y * 64;
    __shared__ float t[64][65];
    const int tid = threadIdx.x;

    #pragma unroll
    for (int it = 0; it < 4; ++it) {
        const int id = it * 256 + tid;
        const int c = id >> 4, i4 = (id & 15) * 4;
        const float4_ v = *(const float4_*)&in[(size_t)(c0 + c) * NN + n0 + i4];
        t[c][i4 + 0] = v[0]; t[c][i4 + 1] = v[1];
        t[c][i4 + 2] = v[2]; t[c][i4 + 3] = v[3];
    }
    __syncthreads();

    #pragma unroll
    for (int it = 0; it < 2; ++it) {
        const int id = it * 256 + tid;
        const int n = id >> 3, j8 = (id & 7) * 8;
        short8 sv;
        #pragma unroll
        for (int k = 0; k < 8; ++k) {
            bf16 h = __float2bfloat16(t[j8 + k][n]);
            sv[k] = *reinterpret_cast<short*>(&h);
        }
        *(short8*)&outp[(size_t)(n0 + n) * C_ + c0 + j8] = sv;
    }
}

// ---------------------------------------------------------------------------
// kgemm: Y[pb][1152][16384] = Wb x Xt[pb], bf16 MFMA. Batch-pair z.
// Proven round-1 structure: 64x128 tile, A+B in LDS (27.6 KB), 4 waves.
// Do NOT enlarge tile (regressed r2/r7) or inline transpose (regressed r9).
// ---------------------------------------------------------------------------
__global__ __launch_bounds__(256) void kgemm(
    const bf16* __restrict__ Wb, const bf16* __restrict__ Xt,
    bf16* __restrict__ Y)
{
    const int nt0 = blockIdx.x * 128;
    const int mt0 = blockIdx.y * 64;
    const int pb  = blockIdx.z;
    const int tid = threadIdx.x;
    const bf16* Xs = Xt + ((size_t)pb * 2 + (mt0 >= 768 ? 1 : 0)) * NN * C_;
    bf16* Yp = Y + (size_t)pb * TOT * NN;

    __shared__ short sA[64][72];
    __shared__ short sB[128][72];

    const int wave = tid >> 6, lane = tid & 63;
    const int mw = (wave & 1) * 32, nw = (wave >> 1) * 64;
    const int lm = lane & 15, lq = lane >> 4;

    float4_ acc[2][4];
    #pragma unroll
    for (int i = 0; i < 2; ++i)
        #pragma unroll
        for (int j = 0; j < 4; ++j)
            acc[i][j] = (float4_){0.f, 0.f, 0.f, 0.f};

    for (int kc = 0; kc < 192; kc += 64) {
        __syncthreads();
        {
            int r = tid >> 3, c8 = (tid & 7) * 8;
            #pragma unroll
            for (int it = 0; it < 2; ++it, r += 32)
                *(short8*)&sA[r][c8] =
                    *(const short8*)&Wb[(size_t)(mt0 + r) * C_ + kc + c8];
        }
        {
            int r = tid >> 3, c8 = (tid & 7) * 8;
            #pragma unroll
            for (int it = 0; it < 4; ++it, r += 32)
                *(short8*)&sB[r][c8] =
                    *(const short8*)&Xs[(size_t)(nt0 + r) * C_ + kc + c8];
        }
        __syncthreads();
        #pragma unroll
        for (int kk = 0; kk < 64; kk += 32) {
            short8 af[2], bfr[4];
            const int ko = kk + lq * 8;
            #pragma unroll
            for (int i = 0; i < 2; ++i)
                af[i] = *(const short8*)&sA[mw + i * 16 + lm][ko];
            #pragma unroll
            for (int j = 0; j < 4; ++j)
                bfr[j] = *(const short8*)&sB[nw + j * 16 + lm][ko];
            #pragma unroll
            for (int i = 0; i < 2; ++i)
                #pragma unroll
                for (int j = 0; j < 4; ++j)
                    acc[i][j] = __builtin_amdgcn_mfma_f32_16x16x32_bf16(
                        af[i], bfr[j], acc[i][j], 0, 0, 0);
        }
    }
    #pragma unroll
    for (int i = 0; i < 2; ++i)
        #pragma unroll
        for (int j = 0; j < 4; ++j) {
            const int n = nt0 + nw + j * 16 + lm;
            #pragma unroll
            for (int r = 0; r < 4; ++r) {
                const int m = mt0 + mw + i * 16 + lq * 4 + r;
                Yp[(size_t)m * NN + n] = __float2bfloat16(acc[i][j][r]);
            }
        }
}

// ---------------------------------------------------------------------------
// kdw: depthwise 3x3 Y[pb] -> QT[p*2+pb], register-resident row-sliding.
// Batch-pair z. Halo via lane shuffles (bit-exact).
// ---------------------------------------------------------------------------
__device__ __forceinline__ void kdw_load_row(
    float* r, const bf16* __restrict__ Yc, int row, int x0, int lane)
{
    float f[8];
    if (row >= 0 && row <= 127) {
        short8 v = *(const short8*)(Yc + row * 128 + x0);
        #pragma unroll
        for (int i = 0; i < 8; ++i) f[i] = s2f(v[i]);
    } else {
        #pragma unroll
        for (int i = 0; i < 8; ++i) f[i] = 0.f;
    }
    const float lf = __shfl(f[7], lane - 1);
    const float rf = __shfl(f[0], lane + 1);
    r[0] = (x0 > 0)   ? lf : 0.f;
    r[9] = (x0 < 120) ? rf : 0.f;
    #pragma unroll
    for (int i = 0; i < 8; ++i) r[i + 1] = f[i];
}

__global__ __launch_bounds__(256) void kdw(
    const bf16* __restrict__ Y,
    const float* __restrict__ qkv_dw, const float* __restrict__ qm_dw,
    const float* __restrict__ kvm_dw, int p, bf16* __restrict__ QT,
    float* __restrict__ nrmsq)
{
    const int ch  = blockIdx.x;
    const int pb  = blockIdx.z;
    const int b   = p * 2 + pb;
    const int tid = threadIdx.x;
    const int tx = tid & 15, ty = tid >> 4;
    const int lane = tid & 63;
    const int x0 = tx * 8;
    const int y0 = blockIdx.y * 64 + ty * 4;

    const float* dwp = (ch < 576) ? qkv_dw + (size_t)ch * 9
                     : (ch < 768) ? qm_dw + (size_t)(ch - 576) * 9
                                  : kvm_dw + (size_t)(ch - 768) * 9;
    float w[9];
    #pragma unroll
    for (int i = 0; i < 9; ++i) w[i] = dwp[i];

    const bf16* Yc = Y + ((size_t)pb * TOT + ch) * NN;
    bf16* qout = QT + ((size_t)b * TOT + ch) * NN;

    float r0[10], r1[10], r2[10];
    kdw_load_row(r0, Yc, y0 - 1, x0, lane);
    kdw_load_row(r1, Yc, y0,     x0, lane);

    float ssq = 0.f;
    #pragma unroll
    for (int yy = 0; yy < 4; ++yy) {
        kdw_load_row(r2, Yc, y0 + yy + 1, x0, lane);
        short8 sv;
        #pragma unroll
        for (int xx = 0; xx < 8; ++xx) {
            float s = w[0] * r0[xx] + w[1] * r0[xx + 1] + w[2] * r0[xx + 2]
                    + w[3] * r1[xx] + w[4] * r1[xx + 1] + w[5] * r1[xx + 2]
                    + w[6] * r2[xx] + w[7] * r2[xx + 1] + w[8] * r2[xx + 2];
            ssq += s * s;
            bf16 h = __float2bfloat16(s);
            sv[xx] = *reinterpret_cast<short*>(&h);
        }
        *(short8*)&qout[(size_t)(y0 + yy) * 128 + x0] = sv;
        #pragma unroll
        for (int i = 0; i < 10; ++i) { r0[i] = r1[i]; r1[i] = r2[i]; }
    }

    // fused sum-of-squares for norm classes q/k/q_mut/k_mut
    int cls = -1, ci = 0;
    if (ch < 192)                    { cls = 0; ci = ch; }
    else if (ch < 384)               { cls = 1; ci = ch - 192; }
    else if (ch >= 576 && ch < 768)  { cls = 2; ci = ch - 576; }
    else if (ch >= 768 && ch < 960)  { cls = 3; ci = ch - 768; }
    if (cls >= 0) {
        #pragma unroll
        for (int off = 32; off > 0; off >>= 1) ssq += __shfl_down(ssq, off);
        __shared__ float red[4];
        if ((tid & 63) == 0) red[tid >> 6] = ssq;
        __syncthreads();
        if (tid == 0)
            atomicAdd(&nrmsq[(b * 4 + cls) * 192 + ci],
                      red[0] + red[1] + red[2] + red[3]);
    }
}

// ---------------------------------------------------------------------------
// k3_mfma: Gram partials via MFMA, operands direct from global.
// grid (32 n-chunks of 512, 8 = t*4+h, 4 b), block 256 = 4 waves.
// ---------------------------------------------------------------------------
__global__ __launch_bounds__(256) void k3_mfma(
    const bf16* __restrict__ QT, float* __restrict__ Gpart)
{
    const int chunk = blockIdx.x;
    const int t = blockIdx.y >> 2, h = blockIdx.y & 3;
    const int b = blockIdx.z;
    const int qch = (t == 0 ? 0 : 576) + h * CHD;
    const int kch = (t == 0 ? 192 : 768) + h * CHD;
    const bf16* qp = QT + ((size_t)b * TOT + qch) * NN;
    const bf16* kp = QT + ((size_t)b * TOT + kch) * NN;

    const int tid = threadIdx.x;
    const int wave = tid >> 6, lane = tid & 63;
    const int lm = lane & 15, lq = lane >> 4;
    const int n0 = chunk * 512 + wave * 128;

    float4_ acc[3][3];
    #pragma unroll
    for (int i = 0; i < 3; ++i)
        #pragma unroll
        for (int j = 0; j < 3; ++j)
            acc[i][j] = (float4_){0.f, 0.f, 0.f, 0.f};

    #pragma unroll
    for (int kk = 0; kk < 128; kk += 32) {
        short8 af[3], bfr[3];
        const int ko = n0 + kk + lq * 8;
        #pragma unroll
        for (int i = 0; i < 3; ++i)
            af[i] = *(const short8*)&qp[(size_t)(i * 16 + lm) * NN + ko];
        #pragma unroll
        for (int j = 0; j < 3; ++j)
            bfr[j] = *(const short8*)&kp[(size_t)(j * 16 + lm) * NN + ko];
        #pragma unroll
        for (int i = 0; i < 3; ++i)
            #pragma unroll
            for (int j = 0; j < 3; ++j)
                acc[i][j] = __builtin_amdgcn_mfma_f32_16x16x32_bf16(
                    af[i], bfr[j], acc[i][j], 0, 0, 0);
    }

    __shared__ float sW[4][48 * 49];
    #pragma unroll
    for (int i = 0; i < 3; ++i)
        #pragma unroll
        for (int j = 0; j < 3; ++j)
            #pragma unroll
            for (int r = 0; r < 4; ++r)
                sW[wave][(i * 16 + lq * 4 + r) * 49 + j * 16 + lm] = acc[i][j][r];
    __syncthreads();

    const int gidx = ((t * 4 + b) * 4 + h);
    float* Gp = Gpart + ((size_t)gidx * 32 + chunk) * 2304;
    for (int idx = tid; idx < 2304; idx += 256) {
        const int c = idx / 48, d = idx % 48;
        Gp[idx] = sW[0][c * 49 + d] + sW[1][c * 49 + d]
                + sW[2][c * 49 + d] + sW[3][c * 49 + d];
    }
}

// ---------------------------------------------------------------------------
// kred: G[gidx][2304] = sum over 32 chunks of Gpart[gidx][chunk][2304].
// 288 blocks — keep the tail parallel (round-10 lesson).
// ---------------------------------------------------------------------------
__global__ __launch_bounds__(256) void kred(
    const float* __restrict__ Gpart, float* __restrict__ G)
{
    const int idx = blockIdx.x * 256 + threadIdx.x;
    if (idx >= 32 * 2304) return;
    const int g = idx / 2304, i = idx % 2304;
    const float* p = Gpart + (size_t)g * 32 * 2304 + i;
    float s = 0.f;
    #pragma unroll
    for (int ch = 0; ch < 32; ++ch) s += p[(size_t)ch * 2304];
    G[(size_t)g * 2304 + i] = s;
}

// ---------------------------------------------------------------------------
// k4a_softmax: wave-per-row softmax of the 32 48x48 logit matrices.
// ---------------------------------------------------------------------------
__global__ __launch_bounds__(256) void k4a_softmax(
    const float* __restrict__ G, const float* __restrict__ nrmsq,
    const float* __restrict__ tq, const float* __restrict__ tm,
    float* __restrict__ P)
{
    const int gidx = blockIdx.x;            // (t*4 + b)*4 + h
    const int h = gidx & 3, tb = gidx >> 2;
    const int b = tb & 3, t = tb >> 2;
    const float* Gp = G + (size_t)gidx * 2304;
    float* Pp = P + (size_t)gidx * 2304;

    const int tid = threadIdx.x;
    const int wave = tid >> 6, lane = tid & 63;
    const int clsq = (t == 0) ? 0 : 2, clsk = (t == 0) ? 1 : 3;
    const float tmp = (t == 0 ? tq[h] : tm[h]);

    float nk = 1.f;
    if (lane < 48)
        nk = fmaxf(sqrtf(fmaxf(nrmsq[(b * 4 + clsk) * 192 + h * 48 + lane], 0.f)),
                   1e-12f);
    const float sk = tmp / nk;   // per-lane (per-d) scale

    const int c0 = blockIdx.y * 12 + wave * 3;
    #pragma unroll
    for (int cc = 0; cc < 3; ++cc) {
        const int c = c0 + cc;
        const float nq =
            fmaxf(sqrtf(fmaxf(nrmsq[(b * 4 + clsq) * 192 + h * 48 + c], 0.f)),
                  1e-12f);
        float L = -1e30f;
        if (lane < 48) L = Gp[c * 48 + lane] * sk / nq;
        float mx = L;
        #pragma unroll
        for (int off = 32; off > 0; off >>= 1)
            mx = fmaxf(mx, __shfl_xor(mx, off));
        float e = (lane < 48) ? expf(L - mx) : 0.f;
        float sum = e;
        #pragma unroll
        for (int off = 32; off > 0; off >>= 1)
            sum += __shfl_xor(sum, off);
        if (lane < 48) Pp[c * 48 + lane] = e / sum;
    }
}

// ---------------------------------------------------------------------------
// k4b_fold: Mb[b][o][t*192+h*48+d] = sum_c proj[o][t*192+h*48+c] * P[c][d].
// ---------------------------------------------------------------------------
__global__ __launch_bounds__(256) void k4b_fold(
    const float* __restrict__ P, const float* __restrict__ proj_w,
    bf16* __restrict__ Mb)
{
    const int gidx = blockIdx.x;
    const int h = gidx & 3, tb = gidx >> 2;
    const int b = tb & 3, t = tb >> 2;
    const int o0 = blockIdx.y * 48;
    const int colb = t * 192 + h * 48;

    __shared__ float sP[48][49];   // sP[c][d]
    __shared__ float sW[48][49];   // sW[o_local][c]
    const int tid = threadIdx.x;
    const float* Pp = P + (size_t)gidx * 2304;

    for (int idx = tid; idx < 2304; idx += 256) {
        const int r = idx / 48, q = idx % 48;
        sP[r][q] = Pp[idx];
        sW[r][q] = proj_w[(size_t)(o0 + r) * 384 + colb + q];
    }
    __syncthreads();

    for (int idx = tid; idx < 2304; idx += 256) {
        const int o = idx / 48, d = idx % 48;
        float s = 0.f;
        #pragma unroll
        for (int c = 0; c < 48; ++c) s += sW[o][c] * sP[c][d];
        Mb[((size_t)b * 192 + o0 + o) * 384 + colb + d] = __float2bfloat16(s);
    }
}

// ---------------------------------------------------------------------------
// k5_mfma: out[b][192][16384] = Mb[b][192][384] x V, V taken DIRECTLY from
// QT (v = ch 384..575, v_mut = ch 960..1151) with transpose done in the LDS
// staging step -> no ktv kernel / Vt buffer.
// ---------------------------------------------------------------------------
__global__ __launch_bounds__(512, 4) void k5_mfma(
    const bf16* __restrict__ Mb, const bf16* __restrict__ QT,
    float* __restrict__ out)
{
    const int nt0 = blockIdx.x * 128;
    const int b   = blockIdx.z;
    const int tid = threadIdx.x;

    __shared__ short sM[192][72];
    __shared__ short sB[128][72];   // [n][d_local]

    const int wave = tid >> 6, lane = tid & 63;
    const int wm = (wave >> 2) * 96;   // 0 / 96
    const int wn = (wave & 3) * 32;    // 0 / 32 / 64 / 96
    const int lm = lane & 15, lq = lane >> 4;

    const bf16* Qb = QT + (size_t)b * TOT * NN;
    const bf16* Mp = Mb + (size_t)b * 192 * 384;

    float4_ acc[6][2];
    #pragma unroll
    for (int i = 0; i < 6; ++i)
        #pragma unroll
        for (int j = 0; j < 2; ++j)
            acc[i][j] = (float4_){0.f, 0.f, 0.f, 0.f};

    for (int kc = 0; kc < 384; kc += 64) {
        __syncthreads();
        // stage M tile: 192 rows x 64 k (1536 short8 granules, 3/thread)
        #pragma unroll
        for (int it = 0; it < 3; ++it) {
            const int id = it * 512 + tid;
            const int r = id >> 3, g = (id & 7) * 8;
            *(short8*)&sM[r][g] =
                *(const short8*)&Mp[(size_t)r * 384 + kc + g];
        }
        // stage V tile transposed from QT: channels chbase..chbase+63.
        const int chbase = (kc < 192) ? (384 + kc) : (960 + (kc - 192));
        #pragma unroll
        for (int it = 0; it < 2; ++it) {
            const int t = it * 512 + tid;
            const int d = t & 63, ng = t >> 6;
            short8 v = *(const short8*)
                &Qb[(size_t)(chbase + d) * NN + nt0 + ng * 8];
            #pragma unroll
            for (int j = 0; j < 8; ++j)
                sB[ng * 8 + j][d] = v[j];
        }
        __syncthreads();
        #pragma unroll
        for (int kk = 0; kk < 64; kk += 32) {
            short8 af[6], bfr[2];
            const int ko = kk + lq * 8;
            #pragma unroll
            for (int i = 0; i < 6; ++i)
                af[i] = *(const short8*)&sM[wm + i * 16 + lm][ko];
            #pragma unroll
            for (int j = 0; j < 2; ++j)
                bfr[j] = *(const short8*)&sB[wn + j * 16 + lm][ko];
            #pragma unroll
            for (int i = 0; i < 6; ++i)
                #pragma unroll
                for (int j = 0; j < 2; ++j)
                    acc[i][j] = __builtin_amdgcn_mfma_f32_16x16x32_bf16(
                        af[i], bfr[j], acc[i][j], 0, 0, 0);
        }
    }
    #pragma unroll
    for (int i = 0; i < 6; ++i)
        #pragma unroll
        for (int j = 0; j < 2; ++j) {
            const int n = nt0 + wn + j * 16 + lm;
            #pragma unroll
            for (int r = 0; r < 4; ++r) {
                const int m = wm + i * 16 + lq * 4 + r;
                out[((size_t)b * C_ + m) * NN + n] = acc[i][j][r];
            }
        }
}

// ---------------------------------------------------------------------------
extern "C" void kernel_launch(void* const* d_in, const int* in_sizes, int n_in,
                              void* d_out, int out_size, void* d_ws, size_t ws_size,
                              hipStream_t stream)
{
    const float* x     = (const float*)d_in[0];
    const float* xh    = (const float*)d_in[1];
    const float* qkvw  = (const float*)d_in[2];
    const float* qkvdw = (const float*)d_in[3];
    const float* qmw   = (const float*)d_in[4];
    const float* qmdw  = (const float*)d_in[5];
    const float* kvmw  = (const float*)d_in[6];
    const float* kvmdw = (const float*)d_in[7];
    const float* projw = (const float*)d_in[8];
    const float* tq    = (const float*)d_in[9];
    const float* tm    = (const float*)d_in[10];
    float* out = (float*)d_out;

    char* ws = (char*)d_ws;
    size_t off = 0;
    bf16*  QT = (bf16*)(ws + off);  off += (size_t)B_ * TOT * NN * 2;     // 144 MiB
    bf16*  Y  = (bf16*)(ws + off);  off += (size_t)2 * TOT * NN * 2;      // 72 MiB (pair)
    bf16*  Xt = (bf16*)(ws + off);  off += (size_t)2 * 2 * NN * C_ * 2;   // 24 MiB (pair)
    bf16*  Wb = (bf16*)(ws + off);  off += (size_t)TOT * C_ * 2;
    float* nrm = (float*)(ws + off); off += (size_t)B_ * 4 * 192 * 4;
    float* G   = (float*)(ws + off); off += (size_t)2 * B_ * HEADS * 48 * 48 * 4;
    bf16*  Mb  = (bf16*)(ws + off);  off += (size_t)B_ * 192 * 384 * 2;
    float* Gpart = (float*)(ws + off); off += (size_t)32 * 32 * 2304 * 4;  // 9 MiB
    float* P = Gpart;  // softmax probs overlay Gpart (dead after kred/k4a)

    hipMemsetAsync(nrm, 0, (size_t)B_ * 4 * 192 * 4, stream);

    kprep_w<<<dim3((TOT * C_ + 255) / 256), 256, 0, stream>>>(qkvw, qmw, kvmw, Wb);

    for (int p = 0; p < 2; ++p) {                 // batch pairs
        kprep_x<<<dim3(256, 3, 4), 256, 0, stream>>>(x, xh, p, Xt);
        kgemm  <<<dim3(128, 18, 2), 256, 0, stream>>>(Wb, Xt, Y);
        kdw    <<<dim3(1152, 2, 2), 256, 0, stream>>>(Y, qkvdw, qmdw, kvmdw, p, QT, nrm);
    }

    k3_mfma    <<<dim3(32, 8, B_), 256, 0, stream>>>(QT, Gpart);
    kred       <<<dim3((32 * 2304 + 255) / 256), 256, 0, stream>>>(Gpart, G);
    k4a_softmax<<<dim3(32, 4), 256, 0, stream>>>(G, nrm, tq, tm, P);
    k4b_fold   <<<dim3(32, 4), 256, 0, stream>>>(P, projw, Mb);
    k5_mfma    <<<dim3(128, 1, B_), 512, 0, stream>>>(Mb, QT, out);
}